// Round 1
// baseline (606.070 us; speedup 1.0000x reference)
//
#include <hip/hip_runtime.h>
#include <cstdint>

// ---------------------------------------------------------------------------
// Qwen2 attention block, MI355X/gfx950. Round 0: correctness-first baseline.
// Pipeline: cast->bf16, QKV GEMM (MFMA), RoPE+reorder, V-transpose,
//           flash causal GQA attention (MFMA), O-proj GEMM -> f32 out.
// ---------------------------------------------------------------------------

typedef short bf16x8 __attribute__((ext_vector_type(8)));
typedef float f32x4 __attribute__((ext_vector_type(4)));

static constexpr int Bsz = 2, Ssz = 2048, Hsz = 2048;
static constexpr int NH = 16, NKV = 4, HD = 128;
static constexpr int Mrows = Bsz * Ssz;              // 4096
static constexpr int NQKV = (NH + 2 * NKV) * HD;     // 3072
static constexpr float SCALE = 0.08838834764831845f; // HD^-0.5

__device__ __forceinline__ unsigned short f2bf(float f) {
  union { float f; unsigned u; } x; x.f = f;
  unsigned r = x.u + 0x7fffu + ((x.u >> 16) & 1u);   // RNE
  return (unsigned short)(r >> 16);
}
__device__ __forceinline__ float b2f(unsigned short h) {
  union { unsigned u; float f; } x; x.u = ((unsigned)h) << 16;
  return x.f;
}

// async global->LDS, 16B per lane. lds must be wave-uniform; HW adds lane*16.
__device__ __forceinline__ void gload_lds16(const void* g, void* lds) {
  auto gp = reinterpret_cast<const __attribute__((address_space(1))) unsigned int*>(
      reinterpret_cast<uintptr_t>(g));
  auto lp = reinterpret_cast<__attribute__((address_space(3))) unsigned int*>(
      static_cast<uint32_t>(reinterpret_cast<uintptr_t>(lds)));
  __builtin_amdgcn_global_load_lds(gp, lp, 16, 0, 0);
}

// ---------------------------------------------------------------------------
__global__ __launch_bounds__(256) void cast_f32_bf16(
    const float* __restrict__ in, unsigned short* __restrict__ out, int n) {
  int i = (blockIdx.x * 256 + threadIdx.x) * 4;
  if (i < n) {
    float4 v = *(const float4*)(in + i);
    ushort4 o;
    o.x = f2bf(v.x); o.y = f2bf(v.y); o.z = f2bf(v.z); o.w = f2bf(v.w);
    *(ushort4*)(out + i) = o;
  }
}

__global__ __launch_bounds__(256) void concat_bias(
    const float* __restrict__ qb, const float* __restrict__ kb,
    const float* __restrict__ vb, float* __restrict__ ob) {
  int i = blockIdx.x * 256 + threadIdx.x;
  if (i < NH * HD) ob[i] = qb[i];
  else if (i < NH * HD + NKV * HD) ob[i] = kb[i - NH * HD];
  else if (i < NQKV) ob[i] = vb[i - NH * HD - NKV * HD];
}

// ---------------------------------------------------------------------------
// C[M][N] = A[M][K] * B[N][K]^T (+bias). 128x128 tile, BK=32, 4 waves (2x2),
// each wave 64x64 = 4x4 fragments of 16x16x32 bf16 MFMA. m97 structure.
__device__ __forceinline__ void store_out(unsigned short* p, size_t i, float v) { p[i] = f2bf(v); }
__device__ __forceinline__ void store_out(float* p, size_t i, float v) { p[i] = v; }

template <typename OutT, bool HAS_BIAS>
__global__ __launch_bounds__(256) void gemm_bt(
    const unsigned short* __restrict__ A, const unsigned short* __restrict__ Bm,
    const float* __restrict__ bias, OutT* __restrict__ C, int K, int N) {
  __shared__ unsigned short As[128 * 32];
  __shared__ unsigned short Bs[128 * 32];
  const int t = threadIdx.x;
  const int lane = t & 63;
  const int l16 = lane & 15, lg = lane >> 4;
  const int w = t >> 6;
  const int wm = (w >> 1) * 64, wn = (w & 1) * 64;
  const int tm = blockIdx.x * 128, tn = blockIdx.y * 128;

  f32x4 acc[4][4] = {};

  for (int k0 = 0; k0 < K; k0 += 32) {
#pragma unroll
    for (int i = 0; i < 2; ++i) {
      int c = i * 256 + t;
      const unsigned short* ga = A + (size_t)(tm + (c >> 2)) * K + k0 + (c & 3) * 8;
      const unsigned short* gb = Bm + (size_t)(tn + (c >> 2)) * K + k0 + (c & 3) * 8;
      gload_lds16(ga, (char*)As + (((c >> 6)) << 10));
      gload_lds16(gb, (char*)Bs + (((c >> 6)) << 10));
    }
    __syncthreads();
    bf16x8 af[4], bfr[4];
#pragma unroll
    for (int m = 0; m < 4; ++m)
      af[m] = *(const bf16x8*)(As + (wm + m * 16 + l16) * 32 + lg * 8);
#pragma unroll
    for (int n = 0; n < 4; ++n)
      bfr[n] = *(const bf16x8*)(Bs + (wn + n * 16 + l16) * 32 + lg * 8);
#pragma unroll
    for (int m = 0; m < 4; ++m)
#pragma unroll
      for (int n = 0; n < 4; ++n)
        acc[m][n] = __builtin_amdgcn_mfma_f32_16x16x32_bf16(af[m], bfr[n], acc[m][n], 0, 0, 0);
    __syncthreads();
  }

#pragma unroll
  for (int m = 0; m < 4; ++m)
#pragma unroll
    for (int n = 0; n < 4; ++n) {
      int col = tn + wn + n * 16 + l16;
      float bv = HAS_BIAS ? bias[col] : 0.0f;
#pragma unroll
      for (int r = 0; r < 4; ++r) {
        int row = tm + wm + m * 16 + lg * 4 + r;
        store_out(C, (size_t)row * N + col, acc[m][n][r] + bv);
      }
    }
}

// ---------------------------------------------------------------------------
// RoPE on Q,K + scatter into head-major layouts.
// QKV [4096][3072] bf16 -> Qr [B][NH][S][HD], Kr [B][NKV][S][HD]
__global__ __launch_bounds__(256) void rope_kernel(
    const unsigned short* __restrict__ QKV, const float* __restrict__ cosp,
    const float* __restrict__ sinp, unsigned short* __restrict__ Qr,
    unsigned short* __restrict__ Kr) {
  int row = blockIdx.x;            // b*S + s
  int b = row >> 11, s = row & 2047;
  const float* cb = cosp + (size_t)row * HD;
  const float* sb = sinp + (size_t)row * HD;
  const unsigned short* src = QKV + (size_t)row * NQKV;
  for (int p = threadIdx.x; p < (NH + NKV) * 64; p += 256) {
    int hh = p >> 6, d = p & 63;
    float c = cb[d], sn = sb[d];
    if (hh < NH) {
      float x1 = b2f(src[hh * HD + d]);
      float x2 = b2f(src[hh * HD + d + 64]);
      size_t o = ((size_t)(b * NH + hh) * Ssz + s) * HD + d;
      Qr[o] = f2bf(x1 * c - x2 * sn);
      Qr[o + 64] = f2bf(x2 * c + x1 * sn);
    } else {
      int g = hh - NH;
      float x1 = b2f(src[NH * HD + g * HD + d]);
      float x2 = b2f(src[NH * HD + g * HD + d + 64]);
      size_t o = ((size_t)(b * NKV + g) * Ssz + s) * HD + d;
      Kr[o] = f2bf(x1 * c - x2 * sn);
      Kr[o + 64] = f2bf(x2 * c + x1 * sn);
    }
  }
}

// V [b][s][g*HD+d] (cols 2560.. of QKV) -> Vt [B][NKV][HD][S]
__global__ __launch_bounds__(256) void vtrans_kernel(
    const unsigned short* __restrict__ QKV, unsigned short* __restrict__ Vt) {
  __shared__ unsigned short tile[32][33];
  int bg = blockIdx.x;             // b*NKV + g
  int s0 = blockIdx.y * 32, d0 = blockIdx.z * 32;
  int b = bg >> 2, g = bg & 3;
  int tx = threadIdx.x & 31, ty = threadIdx.x >> 5;  // 32 x 8
#pragma unroll
  for (int i = 0; i < 4; ++i) {
    int sl = ty + i * 8;
    tile[sl][tx] = QKV[(size_t)(b * Ssz + s0 + sl) * NQKV + (NH + NKV) * HD + g * HD + d0 + tx];
  }
  __syncthreads();
#pragma unroll
  for (int i = 0; i < 4; ++i) {
    int dl = ty + i * 8;
    Vt[((size_t)(b * NKV + g) * HD + d0 + dl) * Ssz + s0 + tx] = tile[tx][dl];
  }
}

// ---------------------------------------------------------------------------
// Flash causal GQA attention. Block = 64 q-rows of one head (4 waves x 16).
// KBLK=32. Per wave: scores (16x32) via MFMA, online softmax (shfl_xor over
// 16 lanes), P->LDS transpose, PV via MFMA against Vt. Out bf16 [4096][2048].
__global__ __launch_bounds__(256) void attn_kernel(
    const unsigned short* __restrict__ Qr, const unsigned short* __restrict__ Kr,
    const unsigned short* __restrict__ Vt, unsigned short* __restrict__ O) {
  const int qt = blockIdx.x;       // S/64 tiles
  const int bh = blockIdx.y;       // b*NH + h
  const int b = bh >> 4, h = bh & 15;
  const int g = h >> 2;            // kv head (NREP=4)
  const int wave = threadIdx.x >> 6;
  const int lane = threadIdx.x & 63;
  const int l16 = lane & 15, lg = lane >> 4;
  const int qr0 = qt * 64 + wave * 16;

  const unsigned short* Qh = Qr + (size_t)(b * NH + h) * Ssz * HD;
  const unsigned short* Kh = Kr + (size_t)(b * NKV + g) * Ssz * HD;
  const unsigned short* Vh = Vt + (size_t)(b * NKV + g) * HD * Ssz;

  __shared__ unsigned short Plds[4][16][32];
  unsigned short(*pw)[32] = Plds[wave];

  bf16x8 aq[4];
#pragma unroll
  for (int c = 0; c < 4; ++c)
    aq[c] = *(const bf16x8*)(Qh + (size_t)(qr0 + l16) * HD + c * 32 + lg * 8);

  f32x4 acco[8] = {};
  float m_r[4], s_r[4];
#pragma unroll
  for (int r = 0; r < 4; ++r) { m_r[r] = -INFINITY; s_r[r] = 0.0f; }

  const int kend = qr0 + 16;       // exclusive causal bound for this wave
  for (int k0 = 0; k0 < kend; k0 += 32) {
    f32x4 sc0 = {}, sc1 = {};
#pragma unroll
    for (int c = 0; c < 4; ++c) {
      bf16x8 bk0 = *(const bf16x8*)(Kh + (size_t)(k0 + l16) * HD + c * 32 + lg * 8);
      bf16x8 bk1 = *(const bf16x8*)(Kh + (size_t)(k0 + 16 + l16) * HD + c * 32 + lg * 8);
      sc0 = __builtin_amdgcn_mfma_f32_16x16x32_bf16(aq[c], bk0, sc0, 0, 0, 0);
      sc1 = __builtin_amdgcn_mfma_f32_16x16x32_bf16(aq[c], bk1, sc1, 0, 0, 0);
    }
    // scale + causal mask + online softmax (rows r: qrow = qr0 + lg*4 + r)
#pragma unroll
    for (int r = 0; r < 4; ++r) {
      int qrow = qr0 + lg * 4 + r;
      float v0 = sc0[r] * SCALE; if (k0 + l16 > qrow) v0 = -1e30f;
      float v1 = sc1[r] * SCALE; if (k0 + 16 + l16 > qrow) v1 = -1e30f;
      float mx = fmaxf(v0, v1);
#pragma unroll
      for (int off = 1; off < 16; off <<= 1) mx = fmaxf(mx, __shfl_xor(mx, off, 64));
      float mnew = fmaxf(m_r[r], mx);
      float f = __expf(m_r[r] - mnew);
      m_r[r] = mnew;
      float e0 = __expf(v0 - mnew);
      float e1 = __expf(v1 - mnew);
      float rs = e0 + e1;
#pragma unroll
      for (int off = 1; off < 16; off <<= 1) rs += __shfl_xor(rs, off, 64);
      s_r[r] = s_r[r] * f + rs;
#pragma unroll
      for (int dt = 0; dt < 8; ++dt) acco[dt][r] *= f;
      pw[lg * 4 + r][l16] = f2bf(e0);
      pw[lg * 4 + r][16 + l16] = f2bf(e1);
    }
    asm volatile("s_waitcnt lgkmcnt(0)" ::: "memory");
    __builtin_amdgcn_sched_barrier(0);
    bf16x8 ap = *(const bf16x8*)(&pw[l16][lg * 8]);
#pragma unroll
    for (int dt = 0; dt < 8; ++dt) {
      bf16x8 bv = *(const bf16x8*)(Vh + (size_t)(dt * 16 + l16) * Ssz + k0 + lg * 8);
      acco[dt] = __builtin_amdgcn_mfma_f32_16x16x32_bf16(ap, bv, acco[dt], 0, 0, 0);
    }
  }

#pragma unroll
  for (int dt = 0; dt < 8; ++dt)
#pragma unroll
    for (int r = 0; r < 4; ++r) {
      int q = qr0 + lg * 4 + r;
      float val = acco[dt][r] / s_r[r];
      O[(size_t)(b * Ssz + q) * (NH * HD) + h * HD + dt * 16 + l16] = f2bf(val);
    }
}

// ---------------------------------------------------------------------------
extern "C" void kernel_launch(void* const* d_in, const int* in_sizes, int n_in,
                              void* d_out, int out_size, void* d_ws, size_t ws_size,
                              hipStream_t stream) {
  const float* hs   = (const float*)d_in[0];
  const float* cosp = (const float*)d_in[1];
  const float* sinp = (const float*)d_in[2];
  // d_in[3] attention_mask: pure causal, handled analytically
  const float* q_w = (const float*)d_in[4];
  const float* q_b = (const float*)d_in[5];
  const float* k_w = (const float*)d_in[6];
  const float* k_b = (const float*)d_in[7];
  const float* v_w = (const float*)d_in[8];
  const float* v_b = (const float*)d_in[9];
  const float* o_w = (const float*)d_in[10];
  float* out = (float*)d_out;

  char* p = (char*)d_ws;
  unsigned short* Xb   = (unsigned short*)p; p += (size_t)Mrows * Hsz * 2;
  unsigned short* Wqkv = (unsigned short*)p; p += (size_t)NQKV * Hsz * 2;
  unsigned short* Wo   = (unsigned short*)p; p += (size_t)Hsz * Hsz * 2;
  unsigned short* QKV  = (unsigned short*)p; p += (size_t)Mrows * NQKV * 2;
  unsigned short* Qr   = (unsigned short*)p; p += (size_t)Bsz * NH * Ssz * HD * 2;
  unsigned short* Kr   = (unsigned short*)p; p += (size_t)Bsz * NKV * Ssz * HD * 2;
  unsigned short* Vt   = (unsigned short*)p; p += (size_t)Bsz * NKV * HD * Ssz * 2;
  unsigned short* Obuf = (unsigned short*)p; p += (size_t)Mrows * Hsz * 2;
  float* biasQKV = (float*)p; p += (size_t)NQKV * 4;

  // casts
  cast_f32_bf16<<<Mrows * Hsz / 1024, 256, 0, stream>>>(hs, Xb, Mrows * Hsz);
  cast_f32_bf16<<<NH * HD * Hsz / 1024, 256, 0, stream>>>(q_w, Wqkv, NH * HD * Hsz);
  cast_f32_bf16<<<NKV * HD * Hsz / 1024, 256, 0, stream>>>(
      k_w, Wqkv + (size_t)NH * HD * Hsz, NKV * HD * Hsz);
  cast_f32_bf16<<<NKV * HD * Hsz / 1024, 256, 0, stream>>>(
      v_w, Wqkv + (size_t)(NH + NKV) * HD * Hsz, NKV * HD * Hsz);
  cast_f32_bf16<<<Hsz * Hsz / 1024, 256, 0, stream>>>(o_w, Wo, Hsz * Hsz);
  concat_bias<<<(NQKV + 255) / 256, 256, 0, stream>>>(q_b, k_b, v_b, biasQKV);

  // QKV projection
  gemm_bt<unsigned short, true><<<dim3(Mrows / 128, NQKV / 128), 256, 0, stream>>>(
      Xb, Wqkv, biasQKV, QKV, Hsz, NQKV);

  // RoPE + reorder + V transpose
  rope_kernel<<<Mrows, 256, 0, stream>>>(QKV, cosp, sinp, Qr, Kr);
  vtrans_kernel<<<dim3(Bsz * NKV, Ssz / 32, HD / 32), 256, 0, stream>>>(QKV, Vt);

  // attention
  attn_kernel<<<dim3(Ssz / 64, Bsz * NH), 256, 0, stream>>>(Qr, Kr, Vt, Obuf);

  // output projection -> f32
  gemm_bt<float, false><<<dim3(Mrows / 128, Hsz / 128), 256, 0, stream>>>(
      Obuf, Wo, nullptr, out, Hsz, Hsz);
}

// Round 2
// 397.662 us; speedup vs baseline: 1.5241x; 1.5241x over previous
//
#include <hip/hip_runtime.h>
#include <cstdint>

// ---------------------------------------------------------------------------
// Qwen2 attention block, MI355X/gfx950. Round 1: attention rework —
// XCD-pinned KV groups (L2 residency), causal pair load-balance, KBLK=64,
// base-2 softmax with in-lane pre-reduction, V prefetch into registers.
// ---------------------------------------------------------------------------

typedef short bf16x8 __attribute__((ext_vector_type(8)));
typedef float f32x4 __attribute__((ext_vector_type(4)));

static constexpr int Bsz = 2, Ssz = 2048, Hsz = 2048;
static constexpr int NH = 16, NKV = 4, HD = 128;
static constexpr int Mrows = Bsz * Ssz;              // 4096
static constexpr int NQKV = (NH + 2 * NKV) * HD;     // 3072
static constexpr float SCALE = 0.08838834764831845f; // HD^-0.5
static constexpr float SC2 = 0.08838834764831845f * 1.4426950408889634f; // *log2(e)

__device__ __forceinline__ unsigned short f2bf(float f) {
  union { float f; unsigned u; } x; x.f = f;
  unsigned r = x.u + 0x7fffu + ((x.u >> 16) & 1u);   // RNE
  return (unsigned short)(r >> 16);
}
__device__ __forceinline__ float b2f(unsigned short h) {
  union { unsigned u; float f; } x; x.u = ((unsigned)h) << 16;
  return x.f;
}

// async global->LDS, 16B per lane. lds must be wave-uniform; HW adds lane*16.
__device__ __forceinline__ void gload_lds16(const void* g, void* lds) {
  auto gp = reinterpret_cast<const __attribute__((address_space(1))) unsigned int*>(
      reinterpret_cast<uintptr_t>(g));
  auto lp = reinterpret_cast<__attribute__((address_space(3))) unsigned int*>(
      static_cast<uint32_t>(reinterpret_cast<uintptr_t>(lds)));
  __builtin_amdgcn_global_load_lds(gp, lp, 16, 0, 0);
}

// ---------------------------------------------------------------------------
__global__ __launch_bounds__(256) void cast_f32_bf16(
    const float* __restrict__ in, unsigned short* __restrict__ out, int n) {
  int i = (blockIdx.x * 256 + threadIdx.x) * 4;
  if (i < n) {
    float4 v = *(const float4*)(in + i);
    ushort4 o;
    o.x = f2bf(v.x); o.y = f2bf(v.y); o.z = f2bf(v.z); o.w = f2bf(v.w);
    *(ushort4*)(out + i) = o;
  }
}

__global__ __launch_bounds__(256) void concat_bias(
    const float* __restrict__ qb, const float* __restrict__ kb,
    const float* __restrict__ vb, float* __restrict__ ob) {
  int i = blockIdx.x * 256 + threadIdx.x;
  if (i < NH * HD) ob[i] = qb[i];
  else if (i < NH * HD + NKV * HD) ob[i] = kb[i - NH * HD];
  else if (i < NQKV) ob[i] = vb[i - NH * HD - NKV * HD];
}

// ---------------------------------------------------------------------------
// C[M][N] = A[M][K] * B[N][K]^T (+bias). 128x128 tile, BK=32, 4 waves (2x2),
// each wave 64x64 = 4x4 fragments of 16x16x32 bf16 MFMA. m97 structure.
__device__ __forceinline__ void store_out(unsigned short* p, size_t i, float v) { p[i] = f2bf(v); }
__device__ __forceinline__ void store_out(float* p, size_t i, float v) { p[i] = v; }

template <typename OutT, bool HAS_BIAS>
__global__ __launch_bounds__(256) void gemm_bt(
    const unsigned short* __restrict__ A, const unsigned short* __restrict__ Bm,
    const float* __restrict__ bias, OutT* __restrict__ C, int K, int N) {
  __shared__ unsigned short As[128 * 32];
  __shared__ unsigned short Bs[128 * 32];
  const int t = threadIdx.x;
  const int lane = t & 63;
  const int l16 = lane & 15, lg = lane >> 4;
  const int w = t >> 6;
  const int wm = (w >> 1) * 64, wn = (w & 1) * 64;
  const int tm = blockIdx.x * 128, tn = blockIdx.y * 128;

  f32x4 acc[4][4] = {};

  for (int k0 = 0; k0 < K; k0 += 32) {
#pragma unroll
    for (int i = 0; i < 2; ++i) {
      int c = i * 256 + t;
      const unsigned short* ga = A + (size_t)(tm + (c >> 2)) * K + k0 + (c & 3) * 8;
      const unsigned short* gb = Bm + (size_t)(tn + (c >> 2)) * K + k0 + (c & 3) * 8;
      gload_lds16(ga, (char*)As + (((c >> 6)) << 10));
      gload_lds16(gb, (char*)Bs + (((c >> 6)) << 10));
    }
    __syncthreads();
    bf16x8 af[4], bfr[4];
#pragma unroll
    for (int m = 0; m < 4; ++m)
      af[m] = *(const bf16x8*)(As + (wm + m * 16 + l16) * 32 + lg * 8);
#pragma unroll
    for (int n = 0; n < 4; ++n)
      bfr[n] = *(const bf16x8*)(Bs + (wn + n * 16 + l16) * 32 + lg * 8);
#pragma unroll
    for (int m = 0; m < 4; ++m)
#pragma unroll
      for (int n = 0; n < 4; ++n)
        acc[m][n] = __builtin_amdgcn_mfma_f32_16x16x32_bf16(af[m], bfr[n], acc[m][n], 0, 0, 0);
    __syncthreads();
  }

#pragma unroll
  for (int m = 0; m < 4; ++m)
#pragma unroll
    for (int n = 0; n < 4; ++n) {
      int col = tn + wn + n * 16 + l16;
      float bv = HAS_BIAS ? bias[col] : 0.0f;
#pragma unroll
      for (int r = 0; r < 4; ++r) {
        int row = tm + wm + m * 16 + lg * 4 + r;
        store_out(C, (size_t)row * N + col, acc[m][n][r] + bv);
      }
    }
}

// ---------------------------------------------------------------------------
// RoPE on Q,K + scatter into head-major layouts.
// QKV [4096][3072] bf16 -> Qr [B][NH][S][HD], Kr [B][NKV][S][HD]
__global__ __launch_bounds__(256) void rope_kernel(
    const unsigned short* __restrict__ QKV, const float* __restrict__ cosp,
    const float* __restrict__ sinp, unsigned short* __restrict__ Qr,
    unsigned short* __restrict__ Kr) {
  int row = blockIdx.x;            // b*S + s
  int b = row >> 11, s = row & 2047;
  const float* cb = cosp + (size_t)row * HD;
  const float* sb = sinp + (size_t)row * HD;
  const unsigned short* src = QKV + (size_t)row * NQKV;
  for (int p = threadIdx.x; p < (NH + NKV) * 64; p += 256) {
    int hh = p >> 6, d = p & 63;
    float c = cb[d], sn = sb[d];
    if (hh < NH) {
      float x1 = b2f(src[hh * HD + d]);
      float x2 = b2f(src[hh * HD + d + 64]);
      size_t o = ((size_t)(b * NH + hh) * Ssz + s) * HD + d;
      Qr[o] = f2bf(x1 * c - x2 * sn);
      Qr[o + 64] = f2bf(x2 * c + x1 * sn);
    } else {
      int g = hh - NH;
      float x1 = b2f(src[NH * HD + g * HD + d]);
      float x2 = b2f(src[NH * HD + g * HD + d + 64]);
      size_t o = ((size_t)(b * NKV + g) * Ssz + s) * HD + d;
      Kr[o] = f2bf(x1 * c - x2 * sn);
      Kr[o + 64] = f2bf(x2 * c + x1 * sn);
    }
  }
}

// V [b][s][g*HD+d] (cols 2560.. of QKV) -> Vt [B][NKV][HD][S]
__global__ __launch_bounds__(256) void vtrans_kernel(
    const unsigned short* __restrict__ QKV, unsigned short* __restrict__ Vt) {
  __shared__ unsigned short tile[32][33];
  int bg = blockIdx.x;             // b*NKV + g
  int s0 = blockIdx.y * 32, d0 = blockIdx.z * 32;
  int b = bg >> 2, g = bg & 3;
  int tx = threadIdx.x & 31, ty = threadIdx.x >> 5;  // 32 x 8
#pragma unroll
  for (int i = 0; i < 4; ++i) {
    int sl = ty + i * 8;
    tile[sl][tx] = QKV[(size_t)(b * Ssz + s0 + sl) * NQKV + (NH + NKV) * HD + g * HD + d0 + tx];
  }
  __syncthreads();
#pragma unroll
  for (int i = 0; i < 4; ++i) {
    int dl = ty + i * 8;
    Vt[((size_t)(b * NKV + g) * HD + d0 + dl) * Ssz + s0 + tx] = tile[tx][dl];
  }
}

// ---------------------------------------------------------------------------
// Flash causal GQA attention, v2.
// 1-D grid of 512 blocks: block_id = kvg + 8*(hr + 4*pr).
//   kvg in 0..7  = b*4 + (h>>2)  -> pins each KV group to one XCD (id%8).
//   hr  in 0..3  = head within group; pr in 0..15 = causal pair index.
// Block processes q-tiles qt=pr and qt=31-pr (64 rows each; 4 waves x 16).
// KBLK=64: 4 score tiles per iter, base-2 online softmax with in-lane
// pre-reduce, V prefetched to regs before softmax, P via padded LDS.
__global__ __launch_bounds__(256, 1) void attn_kernel(
    const unsigned short* __restrict__ Qr, const unsigned short* __restrict__ Kr,
    const unsigned short* __restrict__ Vt, unsigned short* __restrict__ O) {
  const int id = blockIdx.x;
  const int kvg = id & 7, j = id >> 3;
  const int hr = j & 3, pr = j >> 2;
  const int b = kvg >> 2, g = kvg & 3;
  const int h = g * 4 + hr;
  const int wave = threadIdx.x >> 6;
  const int lane = threadIdx.x & 63;
  const int l16 = lane & 15, lg = lane >> 4;

  const unsigned short* Qh = Qr + (size_t)(b * NH + h) * Ssz * HD;
  const unsigned short* Kh = Kr + (size_t)(b * NKV + g) * Ssz * HD;
  const unsigned short* Vh = Vt + (size_t)(b * NKV + g) * HD * Ssz;

  __shared__ unsigned short Plds[4][16][72];   // 72: pad to break bank aliasing
  unsigned short(*pw)[72] = Plds[wave];

#pragma unroll
  for (int t = 0; t < 2; ++t) {
    const int qt = (t == 0) ? pr : (31 - pr);
    const int qr0 = qt * 64 + wave * 16;

    bf16x8 aq[4];
#pragma unroll
    for (int c = 0; c < 4; ++c)
      aq[c] = *(const bf16x8*)(Qh + (size_t)(qr0 + l16) * HD + c * 32 + lg * 8);

    f32x4 acco[8] = {};
    float m_r[4], s_r[4];
#pragma unroll
    for (int r = 0; r < 4; ++r) { m_r[r] = -INFINITY; s_r[r] = 0.0f; }

    const int kend = qr0 + 16;     // exclusive causal bound for this wave
    for (int k0 = 0; k0 < kend; k0 += 64) {
      // ---- QK^T: 4 score tiles (16 k each) x 4 HD chunks
      f32x4 sc[4] = {};
#pragma unroll
      for (int kt = 0; kt < 4; ++kt) {
#pragma unroll
        for (int c = 0; c < 4; ++c) {
          bf16x8 bk = *(const bf16x8*)(Kh + (size_t)(k0 + kt * 16 + l16) * HD + c * 32 + lg * 8);
          sc[kt] = __builtin_amdgcn_mfma_f32_16x16x32_bf16(aq[c], bk, sc[kt], 0, 0, 0);
        }
      }
      // ---- prefetch V fragments (independent of softmax -> latency hides)
      bf16x8 bv[16];
#pragma unroll
      for (int kc = 0; kc < 2; ++kc)
#pragma unroll
        for (int dt = 0; dt < 8; ++dt)
          bv[kc * 8 + dt] =
              *(const bf16x8*)(Vh + (size_t)(dt * 16 + l16) * Ssz + k0 + kc * 32 + lg * 8);

      // ---- base-2 online softmax (rows r: qrow = qr0 + lg*4 + r)
#pragma unroll
      for (int r = 0; r < 4; ++r) {
        int qrow = qr0 + lg * 4 + r;
        float v0 = sc[0][r] * SC2; if (k0 + l16 > qrow)      v0 = -1e30f;
        float v1 = sc[1][r] * SC2; if (k0 + 16 + l16 > qrow) v1 = -1e30f;
        float v2 = sc[2][r] * SC2; if (k0 + 32 + l16 > qrow) v2 = -1e30f;
        float v3 = sc[3][r] * SC2; if (k0 + 48 + l16 > qrow) v3 = -1e30f;
        float mx = fmaxf(fmaxf(v0, v1), fmaxf(v2, v3));
#pragma unroll
        for (int off = 1; off < 16; off <<= 1) mx = fmaxf(mx, __shfl_xor(mx, off, 64));
        float mnew = fmaxf(m_r[r], mx);
        float f = exp2f(m_r[r] - mnew);
        m_r[r] = mnew;
        float e0 = exp2f(v0 - mnew);
        float e1 = exp2f(v1 - mnew);
        float e2 = exp2f(v2 - mnew);
        float e3 = exp2f(v3 - mnew);
        float rs = (e0 + e1) + (e2 + e3);
#pragma unroll
        for (int off = 1; off < 16; off <<= 1) rs += __shfl_xor(rs, off, 64);
        s_r[r] = s_r[r] * f + rs;
#pragma unroll
        for (int dt = 0; dt < 8; ++dt) acco[dt][r] *= f;
        int row = lg * 4 + r;
        pw[row][l16] = f2bf(e0);
        pw[row][16 + l16] = f2bf(e1);
        pw[row][32 + l16] = f2bf(e2);
        pw[row][48 + l16] = f2bf(e3);
      }
      asm volatile("s_waitcnt lgkmcnt(0)" ::: "memory");
      __builtin_amdgcn_sched_barrier(0);
      // ---- PV: P (16x64) x V^T fragments
#pragma unroll
      for (int kc = 0; kc < 2; ++kc) {
        bf16x8 ap = *(const bf16x8*)(&pw[l16][kc * 32 + lg * 8]);
#pragma unroll
        for (int dt = 0; dt < 8; ++dt)
          acco[dt] = __builtin_amdgcn_mfma_f32_16x16x32_bf16(ap, bv[kc * 8 + dt], acco[dt], 0, 0, 0);
      }
    }

#pragma unroll
    for (int dt = 0; dt < 8; ++dt)
#pragma unroll
      for (int r = 0; r < 4; ++r) {
        int q = qr0 + lg * 4 + r;
        float val = acco[dt][r] / s_r[r];
        O[(size_t)(b * Ssz + q) * (NH * HD) + h * HD + dt * 16 + l16] = f2bf(val);
      }
  }
}

// ---------------------------------------------------------------------------
extern "C" void kernel_launch(void* const* d_in, const int* in_sizes, int n_in,
                              void* d_out, int out_size, void* d_ws, size_t ws_size,
                              hipStream_t stream) {
  const float* hs   = (const float*)d_in[0];
  const float* cosp = (const float*)d_in[1];
  const float* sinp = (const float*)d_in[2];
  // d_in[3] attention_mask: pure causal, handled analytically
  const float* q_w = (const float*)d_in[4];
  const float* q_b = (const float*)d_in[5];
  const float* k_w = (const float*)d_in[6];
  const float* k_b = (const float*)d_in[7];
  const float* v_w = (const float*)d_in[8];
  const float* v_b = (const float*)d_in[9];
  const float* o_w = (const float*)d_in[10];
  float* out = (float*)d_out;

  char* p = (char*)d_ws;
  unsigned short* Xb   = (unsigned short*)p; p += (size_t)Mrows * Hsz * 2;
  unsigned short* Wqkv = (unsigned short*)p; p += (size_t)NQKV * Hsz * 2;
  unsigned short* Wo   = (unsigned short*)p; p += (size_t)Hsz * Hsz * 2;
  unsigned short* QKV  = (unsigned short*)p; p += (size_t)Mrows * NQKV * 2;
  unsigned short* Qr   = (unsigned short*)p; p += (size_t)Bsz * NH * Ssz * HD * 2;
  unsigned short* Kr   = (unsigned short*)p; p += (size_t)Bsz * NKV * Ssz * HD * 2;
  unsigned short* Vt   = (unsigned short*)p; p += (size_t)Bsz * NKV * HD * Ssz * 2;
  unsigned short* Obuf = (unsigned short*)p; p += (size_t)Mrows * Hsz * 2;
  float* biasQKV = (float*)p; p += (size_t)NQKV * 4;

  // casts
  cast_f32_bf16<<<Mrows * Hsz / 1024, 256, 0, stream>>>(hs, Xb, Mrows * Hsz);
  cast_f32_bf16<<<NH * HD * Hsz / 1024, 256, 0, stream>>>(q_w, Wqkv, NH * HD * Hsz);
  cast_f32_bf16<<<NKV * HD * Hsz / 1024, 256, 0, stream>>>(
      k_w, Wqkv + (size_t)NH * HD * Hsz, NKV * HD * Hsz);
  cast_f32_bf16<<<NKV * HD * Hsz / 1024, 256, 0, stream>>>(
      v_w, Wqkv + (size_t)(NH + NKV) * HD * Hsz, NKV * HD * Hsz);
  cast_f32_bf16<<<Hsz * Hsz / 1024, 256, 0, stream>>>(o_w, Wo, Hsz * Hsz);
  concat_bias<<<(NQKV + 255) / 256, 256, 0, stream>>>(q_b, k_b, v_b, biasQKV);

  // QKV projection
  gemm_bt<unsigned short, true><<<dim3(Mrows / 128, NQKV / 128), 256, 0, stream>>>(
      Xb, Wqkv, biasQKV, QKV, Hsz, NQKV);

  // RoPE + reorder + V transpose
  rope_kernel<<<Mrows, 256, 0, stream>>>(QKV, cosp, sinp, Qr, Kr);
  vtrans_kernel<<<dim3(Bsz * NKV, Ssz / 32, HD / 32), 256, 0, stream>>>(QKV, Vt);

  // attention: 512 blocks, kv-group pinned to XCD via id%8
  attn_kernel<<<512, 256, 0, stream>>>(Qr, Kr, Vt, Obuf);

  // output projection -> f32
  gemm_bt<float, false><<<dim3(Mrows / 128, Hsz / 128), 256, 0, stream>>>(
      Obuf, Wo, nullptr, out, Hsz, Hsz);
}